// Round 6
// baseline (149.180 us; speedup 1.0000x reference)
//
#include <hip/hip_runtime.h>
#include <math.h>

namespace {

constexpr int S = 100;
constexpr int NR = 800;
constexpr int RPB = 4;           // batch rows per block
constexpr int NTH = 512;         // 8 waves
constexpr int IN_COLS = 2 + S;   // 102
constexpr int OUT_COLS = 3 + NR + 2 + S; // 905
constexpr float RGASF = 8314.46261815324f;
constexpr float ATMF = 101325.0f;

__device__ __forceinline__ float wave_sum(float v) {
#pragma unroll
  for (int off = 32; off; off >>= 1) v += __shfl_xor(v, off);
  return v;
}

__device__ __forceinline__ float elem(const float4& v, int i) {
  return ((const float*)&v)[i];
}

__global__ __launch_bounds__(NTH, 4)
void chem_props_kernel(const float* __restrict__ TPY,
                       const float* __restrict__ mw,
                       const float* __restrict__ nasa_low,
                       const float* __restrict__ nasa_high,
                       const float* __restrict__ eff,
                       const float* __restrict__ i3b,
                       const float* __restrict__ visc_poly,
                       const float* __restrict__ cond_poly,
                       const float* __restrict__ bdiff_poly,
                       float* __restrict__ out)
{
  __shared__ __align__(16) float4 XL[S];   // X[s][b] quad
  __shared__ __align__(16) float4 U1[S];   // X/sqrt(visc)
  __shared__ __align__(16) float4 U2[S];   // X/visc
  __shared__ __align__(16) float4 VL[S];   // visc
  __shared__ float mwl[S];
  __shared__ float2 ilm[S];                // {1/mw, log2(mw)}
  __shared__ float pa[8][2];               // half-row partials (y, y/mw)
  __shared__ float pb[8][5];               // thermo partials
  __shared__ float rs_L[RPB], rs_cfac[RPB], rs_mW[RPB], rs_scale[RPB], rs_T[RPB];
  __shared__ float psum[2][RPB];           // viscosity-sum wave partials

  const int tid = threadIdx.x;
  const int wid = tid >> 6;
  const int lane = tid & 63;
  const int row0 = blockIdx.x * RPB;

  // ======== Early prefetch for worker stages (input-only, hides under A) ===
  float4 eA[4], eB[4], t3q;
  float cA[5][5], cB[5][5];
  const float* ep = nullptr;
  const float* bp = nullptr;
  if (tid < 200) {
    ep = eff + tid * 4;
#pragma unroll
    for (int i = 0; i < 4; ++i) eA[i] = *(const float4*)&ep[(size_t)i * NR];
#pragma unroll
    for (int i = 0; i < 4; ++i) eB[i] = *(const float4*)&ep[(size_t)(4 + i) * NR];
    t3q = *(const float4*)&i3b[tid * 4];
  } else if (tid >= 384 && tid < 484) {
    bp = bdiff_poly + (tid - 384);
#pragma unroll
    for (int jj = 0; jj < 5; ++jj)
#pragma unroll
      for (int d = 0; d < 5; ++d)
        cA[jj][d] = bp[d * 10000 + jj * 100];
#pragma unroll
    for (int jj = 0; jj < 5; ++jj)
#pragma unroll
      for (int d = 0; d < 5; ++d)
        cB[jj][d] = bp[d * 10000 + (5 + jj) * 100];
  }

  if (tid < S) {
    float m = mw[tid];
    mwl[tid] = m;
    ilm[tid] = make_float2(1.0f / m, __log2f(m));
  }
  __syncthreads();

  // ============ Stage A: per-row species state (2 waves per row) ===========
  const int row = wid & 3;
  const int half = wid >> 2;
  const float* rowp = TPY + (size_t)(row0 + row) * IN_COLS;
  float T = fmaxf(rowp[0], 200.0f);
  float P = rowp[1];
  float L = __logf(T);
  const int s = half * 64 + lane;
  const bool valid = (s < S);
  float y = valid ? fmaxf(rowp[2 + s], 0.0f) : 0.0f;
  float im = valid ? ilm[s].x : 0.0f;
  {
    float py = wave_sum(y);
    float pw = wave_sum(y * im);
    if (lane == 0) { pa[wid][0] = py; pa[wid][1] = pw; }
  }
  __syncthreads();
  {
    float T2 = T * T, T3 = T2 * T, T4 = T2 * T2;
    float invT = 1.0f / T;
    float ysum = pa[row][0] + pa[row + 4][0];
    float wsum = pa[row][1] + pa[row + 4][1];
    float invy = 1.0f / ysum;
    float mW = ysum / wsum;
    float cfac = P / (RGASF * T);
    float lnP = __logf(P * (1.0f / ATMF));
    const float* nasa = (T <= 1000.0f) ? nasa_low : nasa_high;

    float cpx = 0.0f, hy = 0.0f, sy = 0.0f, condA = 0.0f, condB = 0.0f;
    if (valid) {
      float yn = y * invy;
      float x = fmaxf(yn * mW * im, 1e-12f);
      const float* a = nasa + s * 7;
      float a0 = a[0], a1 = a[1], a2 = a[2], a3 = a[3],
            a4 = a[4], a5 = a[5], a6 = a[6];
      float cp = a0 + a1 * T + a2 * T2 + a3 * T3 + a4 * T4;
      float Ht = a0 + 0.5f * a1 * T + (1.0f / 3.0f) * a2 * T2
               + 0.25f * a3 * T3 + 0.2f * a4 * T4 + a5 * invT;
      float S0r = a0 * L + a1 * T + 0.5f * a2 * T2
                + (1.0f / 3.0f) * a3 * T3 + 0.25f * a4 * T4 + a6;
      cpx = cp * x;
      hy = Ht * im * yn;
      sy = (S0r - __logf(x) - lnP) * im * yn;

      float v = visc_poly[0 * S + s];
      v = fmaf(v, L, visc_poly[1 * S + s]);
      v = fmaf(v, L, visc_poly[2 * S + s]);
      v = fmaf(v, L, visc_poly[3 * S + s]);
      v = fmaf(v, L, visc_poly[4 * S + s]);
      float c = cond_poly[0 * S + s];
      c = fmaf(c, L, cond_poly[1 * S + s]);
      c = fmaf(c, L, cond_poly[2 * S + s]);
      c = fmaf(c, L, cond_poly[3 * S + s]);
      c = fmaf(c, L, cond_poly[4 * S + s]);
      condA = x * c;
      condB = x / c;
      ((float*)&XL[s])[row] = x;
      ((float*)&VL[s])[row] = v;
      ((float*)&U1[s])[row] = x * __builtin_amdgcn_rsqf(v);
      ((float*)&U2[s])[row] = x * __builtin_amdgcn_rcpf(v);
    }
    float scp = wave_sum(cpx);
    float sh = wave_sum(hy);
    float ss = wave_sum(sy);
    float sca = wave_sum(condA);
    float scb = wave_sum(condB);
    if (lane == 0) {
      pb[wid][0] = scp; pb[wid][1] = sh; pb[wid][2] = ss;
      pb[wid][3] = sca; pb[wid][4] = scb;
      if (half == 0) {
        rs_L[row] = L;
        rs_T[row] = T;
        rs_cfac[row] = cfac;
        rs_mW[row] = mW;
        rs_scale[row] = ATMF / (mW * P);
      }
    }
  }
  __syncthreads();

  // scalar outputs
  if (tid < RPB) {
    const int r = tid;
    float scp = pb[r][0] + pb[r + 4][0];
    float sh  = pb[r][1] + pb[r + 4][1];
    float ss  = pb[r][2] + pb[r + 4][2];
    float sca = pb[r][3] + pb[r + 4][3];
    float scb = pb[r][4] + pb[r + 4][4];
    float* orow = out + (size_t)(row0 + r) * OUT_COLS;
    orow[0] = RGASF * scp;
    orow[1] = RGASF * rs_T[r] * sh;
    orow[2] = RGASF * ss;
    orow[3 + NR + 1] = 0.5f * (sca + 1.0f / scb);
  }

  // ======== Concurrent worker stages (no barriers between them) ===========
  if (tid < 200) {
    // ---- Stage B: depth-2 pipelined (C @ eff)*i3b + (1-i3b) ----
    const int q0 = tid * 4;
    float acc[4][4];
#pragma unroll
    for (int qi = 0; qi < 4; ++qi)
#pragma unroll
      for (int b = 0; b < RPB; ++b) acc[qi][b] = 0.0f;

    for (int g = 0; g < 96; g += 8) {
      // consume eA (s = g..g+3)
#pragma unroll
      for (int si = 0; si < 4; ++si) {
        float4 xq = XL[g + si];
#pragma unroll
        for (int qi = 0; qi < 4; ++qi)
#pragma unroll
          for (int b = 0; b < RPB; ++b)
            acc[qi][b] = fmaf(elem(xq, b), elem(eA[si], qi), acc[qi][b]);
      }
      // reload eA with s = g+8..g+11 (always valid: g<=88 -> s<=99)
#pragma unroll
      for (int i = 0; i < 4; ++i)
        eA[i] = *(const float4*)&ep[(size_t)(g + 8 + i) * NR];
      // consume eB (s = g+4..g+7)
#pragma unroll
      for (int si = 0; si < 4; ++si) {
        float4 xq = XL[g + 4 + si];
#pragma unroll
        for (int qi = 0; qi < 4; ++qi)
#pragma unroll
          for (int b = 0; b < RPB; ++b)
            acc[qi][b] = fmaf(elem(xq, b), elem(eB[si], qi), acc[qi][b]);
      }
      // reload eB with s = g+12..g+15 when valid
      if (g + 12 < 100) {
#pragma unroll
        for (int i = 0; i < 4; ++i)
          eB[i] = *(const float4*)&ep[(size_t)(g + 12 + i) * NR];
      }
    }
    // tail: s = 96..99 held in eA
#pragma unroll
    for (int si = 0; si < 4; ++si) {
      float4 xq = XL[96 + si];
#pragma unroll
      for (int qi = 0; qi < 4; ++qi)
#pragma unroll
        for (int b = 0; b < RPB; ++b)
          acc[qi][b] = fmaf(elem(xq, b), elem(eA[si], qi), acc[qi][b]);
    }

    float cf[RPB];
#pragma unroll
    for (int b = 0; b < RPB; ++b) cf[b] = rs_cfac[b];
#pragma unroll
    for (int qi = 0; qi < 4; ++qi) {
      float tq = elem(t3q, qi);
      float base = 1.0f - tq;
#pragma unroll
      for (int b = 0; b < RPB; ++b)
        out[(size_t)(row0 + b) * OUT_COLS + 3 + q0 + qi] =
            fmaf(acc[qi][b] * cf[b], tq, base);
    }
  } else if (tid >= 256 && tid < 384) {
    // ---- Stage C: viscosity denom + contribution; thread owns row i ----
    const int i = tid - 256;
    float contrib[RPB] = {0.0f, 0.0f, 0.0f, 0.0f};
    if (i < S) {
      const float mwi = mwl[i];
      const float lmi = ilm[i].y;
      float d0[RPB], d1[RPB], d2[RPB];
#pragma unroll
      for (int b = 0; b < RPB; ++b) { d0[b] = 0; d1[b] = 0; d2[b] = 0; }
#pragma unroll 4
      for (int k = 0; k < S; ++k) {
        float2 il = ilm[k];
        float A = 0.35355339059327373f *
                  __builtin_amdgcn_rsqf(1.0f + mwi * il.x);
        float B4 = __builtin_amdgcn_exp2f(0.25f * (il.y - lmi));
        float m1 = A * B4, m2 = m1 * B4;
        float4 xq = XL[k];
        float4 u1q = U1[k];
        float4 u2q = U2[k];
#pragma unroll
        for (int b = 0; b < RPB; ++b) {
          d0[b] = fmaf(A, elem(xq, b), d0[b]);
          d1[b] = fmaf(m1, elem(u1q, b), d1[b]);
          d2[b] = fmaf(m2, elem(u2q, b), d2[b]);
        }
      }
      float4 vq = VL[i];
      float4 xiq = XL[i];
#pragma unroll
      for (int b = 0; b < RPB; ++b) {
        float vi = elem(vq, b);
        float den = d0[b] + 2.0f * sqrtf(vi) * d1[b] + vi * d2[b];
        contrib[b] = elem(xiq, b) * vi * __builtin_amdgcn_rcpf(den);
      }
    }
#pragma unroll
    for (int b = 0; b < RPB; ++b) contrib[b] = wave_sum(contrib[b]);
    if (lane == 0) {
#pragma unroll
      for (int b = 0; b < RPB; ++b) psum[wid - 4][b] = contrib[b];
    }
  } else if (tid >= 384 && tid < 484) {
    // ---- Stage D: depth-2 pipelined mixture diffusion; thread owns k ----
    const int k = tid - 384;
    float Lb[RPB], acc4[RPB];
#pragma unroll
    for (int b = 0; b < RPB; ++b) { Lb[b] = rs_L[b]; acc4[b] = 0.0f; }

    for (int t = 0; t < 20; t += 2) {
      const int j0 = t * 5;
      // consume cA: j = j0..j0+4
#pragma unroll
      for (int jj = 0; jj < 5; ++jj) {
        const int j = j0 + jj;
        float4 xq = XL[j];
        const bool diag = (j == k);
#pragma unroll
        for (int b = 0; b < RPB; ++b) {
          float p = fmaf(cA[jj][0], Lb[b], cA[jj][1]);
          p = fmaf(p, Lb[b], cA[jj][2]);
          p = fmaf(p, Lb[b], cA[jj][3]);
          p = fmaf(p, Lb[b], cA[jj][4]);
          float r = diag ? 0.0f : __builtin_amdgcn_rcpf(p);
          acc4[b] = fmaf(elem(xq, b), r, acc4[b]);
        }
      }
      // reload cA: group t+2
      if (t + 2 < 20) {
#pragma unroll
        for (int jj = 0; jj < 5; ++jj)
#pragma unroll
          for (int d = 0; d < 5; ++d)
            cA[jj][d] = bp[d * 10000 + ((t + 2) * 5 + jj) * 100];
      }
      // consume cB: j = j0+5..j0+9
#pragma unroll
      for (int jj = 0; jj < 5; ++jj) {
        const int j = j0 + 5 + jj;
        float4 xq = XL[j];
        const bool diag = (j == k);
#pragma unroll
        for (int b = 0; b < RPB; ++b) {
          float p = fmaf(cB[jj][0], Lb[b], cB[jj][1]);
          p = fmaf(p, Lb[b], cB[jj][2]);
          p = fmaf(p, Lb[b], cB[jj][3]);
          p = fmaf(p, Lb[b], cB[jj][4]);
          float r = diag ? 0.0f : __builtin_amdgcn_rcpf(p);
          acc4[b] = fmaf(elem(xq, b), r, acc4[b]);
        }
      }
      // reload cB: group t+3
      if (t + 3 < 20) {
#pragma unroll
        for (int jj = 0; jj < 5; ++jj)
#pragma unroll
          for (int d = 0; d < 5; ++d)
            cB[jj][d] = bp[d * 10000 + ((t + 3) * 5 + jj) * 100];
      }
    }

    float4 xkq = XL[k];
    float mwk = mwl[k];
#pragma unroll
    for (int b = 0; b < RPB; ++b) {
      float num = rs_mW[b] - elem(xkq, b) * mwk;   // XjWj
      out[(size_t)(row0 + b) * OUT_COLS + 3 + NR + 2 + k] =
          num * __builtin_amdgcn_rcpf(acc4[b]) * rs_scale[b];
    }
  }
  __syncthreads();

  if (tid < RPB) {
    out[(size_t)(row0 + tid) * OUT_COLS + 3 + NR] =
        psum[0][tid] + psum[1][tid];   // viscosities
  }
}

} // namespace

extern "C" void kernel_launch(void* const* d_in, const int* in_sizes, int n_in,
                              void* d_out, int out_size, void* d_ws, size_t ws_size,
                              hipStream_t stream) {
  const float* TPY        = (const float*)d_in[0];
  const float* mwp        = (const float*)d_in[1];
  const float* nasa_low   = (const float*)d_in[2];
  const float* nasa_high  = (const float*)d_in[3];
  const float* eff        = (const float*)d_in[4];
  const float* i3b        = (const float*)d_in[5];
  const float* visc_poly  = (const float*)d_in[6];
  const float* cond_poly  = (const float*)d_in[7];
  const float* bdiff_poly = (const float*)d_in[8];
  float* out = (float*)d_out;

  const int B = 2048;
  dim3 grid(B / RPB);
  chem_props_kernel<<<grid, NTH, 0, stream>>>(
      TPY, mwp, nasa_low, nasa_high, eff, i3b,
      visc_poly, cond_poly, bdiff_poly, out);
}

// Round 7
// 121.185 us; speedup vs baseline: 1.2310x; 1.2310x over previous
//
#include <hip/hip_runtime.h>
#include <math.h>

namespace {

constexpr int S = 100;
constexpr int NR = 800;
constexpr int RPB = 4;           // batch rows per block-pair
constexpr int NTH = 512;         // 8 waves
constexpr int IN_COLS = 2 + S;   // 102
constexpr int OUT_COLS = 3 + NR + 2 + S; // 905
constexpr float RGASF = 8314.46261815324f;
constexpr float ATMF = 101325.0f;
constexpr size_t PHI_WS_BYTES = 3 * 10000 * sizeof(float);

__device__ __forceinline__ float wave_sum(float v) {
#pragma unroll
  for (int off = 32; off; off >>= 1) v += __shfl_xor(v, off);
  return v;
}

__device__ __forceinline__ float elem(const float4& v, int i) {
  return ((const float*)&v)[i];
}

// Batch-independent Wilke pair constants: m0 = A, m1 = A*B4, m2 = A*B4^2
__global__ __launch_bounds__(256)
void phi_precompute(const float* __restrict__ mw, float* __restrict__ pm) {
  int idx = blockIdx.x * 256 + threadIdx.x;
  if (idx >= 10000) return;
  int i = idx / 100, k = idx % 100;
  float mwi = mw[i], mwk = mw[k];
  float A = 0.35355339059327373f *
            __builtin_amdgcn_rsqf(1.0f + mwi * __builtin_amdgcn_rcpf(mwk));
  float B4 = __builtin_amdgcn_exp2f(0.25f * (__log2f(mwk) - __log2f(mwi)));
  pm[idx] = A;
  pm[10000 + idx] = A * B4;
  pm[20000 + idx] = A * B4 * B4;
}

template <bool PRE>
__global__ __launch_bounds__(NTH, 8)
void chem_props_kernel(const float* __restrict__ TPY,
                       const float* __restrict__ mw,
                       const float* __restrict__ nasa_low,
                       const float* __restrict__ nasa_high,
                       const float* __restrict__ eff,
                       const float* __restrict__ i3b,
                       const float* __restrict__ visc_poly,
                       const float* __restrict__ cond_poly,
                       const float* __restrict__ bdiff_poly,
                       const float* __restrict__ pm,
                       float* __restrict__ out)
{
  __shared__ __align__(16) float4 XL[S];   // X[s][b] quad
  __shared__ __align__(16) float4 U1[S];   // X/sqrt(visc)
  __shared__ __align__(16) float4 U2[S];   // X/visc
  __shared__ __align__(16) float4 VL[S];   // visc
  __shared__ float mwl[S];
  __shared__ float2 ilm[S];                // {1/mw, log2(mw)}
  __shared__ float pa[8][2];               // half-row partials (y, y/mw)
  __shared__ float pb[8][5];               // thermo partials
  __shared__ float rs_L[RPB], rs_cfac[RPB], rs_mW[RPB], rs_scale[RPB], rs_T[RPB];
  __shared__ float psum[2][RPB];           // viscosity-sum wave partials
  __shared__ __align__(16) float xjd[50][RPB]; // D j-half combine

  const int tid = threadIdx.x;
  const int wid = tid >> 6;
  const int lane = tid & 63;
  const int h = blockIdx.x & 1;            // worker half-select
  const int row0 = (blockIdx.x >> 1) * RPB;

  if (tid < S) {
    float m = mw[tid];
    mwl[tid] = m;
    ilm[tid] = make_float2(1.0f / m, __log2f(m));
  }
  __syncthreads();

  // ============ Stage A: per-row species state (2 waves per row) ===========
  const int row = wid & 3;
  const int half = wid >> 2;
  const float* rowp = TPY + (size_t)(row0 + row) * IN_COLS;
  float T = fmaxf(rowp[0], 200.0f);
  float P = rowp[1];
  float L = __logf(T);
  const int s = half * 64 + lane;
  const bool valid = (s < S);
  float y = valid ? fmaxf(rowp[2 + s], 0.0f) : 0.0f;
  float im = valid ? ilm[s].x : 0.0f;
  {
    float py = wave_sum(y);
    float pw = wave_sum(y * im);
    if (lane == 0) { pa[wid][0] = py; pa[wid][1] = pw; }
  }
  __syncthreads();
  {
    float T2 = T * T, T3 = T2 * T, T4 = T2 * T2;
    float invT = 1.0f / T;
    float ysum = pa[row][0] + pa[row + 4][0];
    float wsum = pa[row][1] + pa[row + 4][1];
    float invy = 1.0f / ysum;
    float mW = ysum / wsum;
    float cfac = P / (RGASF * T);
    float lnP = __logf(P * (1.0f / ATMF));
    const float* nasa = (T <= 1000.0f) ? nasa_low : nasa_high;

    float cpx = 0.0f, hy = 0.0f, sy = 0.0f, condA = 0.0f, condB = 0.0f;
    if (valid) {
      float yn = y * invy;
      float x = fmaxf(yn * mW * im, 1e-12f);
      const float* a = nasa + s * 7;
      float a0 = a[0], a1 = a[1], a2 = a[2], a3 = a[3],
            a4 = a[4], a5 = a[5], a6 = a[6];
      float cp = a0 + a1 * T + a2 * T2 + a3 * T3 + a4 * T4;
      float Ht = a0 + 0.5f * a1 * T + (1.0f / 3.0f) * a2 * T2
               + 0.25f * a3 * T3 + 0.2f * a4 * T4 + a5 * invT;
      float S0r = a0 * L + a1 * T + 0.5f * a2 * T2
                + (1.0f / 3.0f) * a3 * T3 + 0.25f * a4 * T4 + a6;
      cpx = cp * x;
      hy = Ht * im * yn;
      sy = (S0r - __logf(x) - lnP) * im * yn;

      float v = visc_poly[0 * S + s];
      v = fmaf(v, L, visc_poly[1 * S + s]);
      v = fmaf(v, L, visc_poly[2 * S + s]);
      v = fmaf(v, L, visc_poly[3 * S + s]);
      v = fmaf(v, L, visc_poly[4 * S + s]);
      float c = cond_poly[0 * S + s];
      c = fmaf(c, L, cond_poly[1 * S + s]);
      c = fmaf(c, L, cond_poly[2 * S + s]);
      c = fmaf(c, L, cond_poly[3 * S + s]);
      c = fmaf(c, L, cond_poly[4 * S + s]);
      condA = x * c;
      condB = x / c;
      ((float*)&XL[s])[row] = x;
      ((float*)&VL[s])[row] = v;
      ((float*)&U1[s])[row] = x * __builtin_amdgcn_rsqf(v);
      ((float*)&U2[s])[row] = x * __builtin_amdgcn_rcpf(v);
    }
    float scp = wave_sum(cpx);
    float sh = wave_sum(hy);
    float ss = wave_sum(sy);
    float sca = wave_sum(condA);
    float scb = wave_sum(condB);
    if (lane == 0) {
      pb[wid][0] = scp; pb[wid][1] = sh; pb[wid][2] = ss;
      pb[wid][3] = sca; pb[wid][4] = scb;
      if (half == 0) {
        rs_L[row] = L;
        rs_T[row] = T;
        rs_cfac[row] = cfac;
        rs_mW[row] = mW;
        rs_scale[row] = ATMF / (mW * P);
      }
    }
  }
  __syncthreads();

  // scalar outputs (h==0 block of each pair owns them)
  if (h == 0 && tid < RPB) {
    const int r = tid;
    float scp = pb[r][0] + pb[r + 4][0];
    float sh  = pb[r][1] + pb[r + 4][1];
    float ss  = pb[r][2] + pb[r + 4][2];
    float sca = pb[r][3] + pb[r + 4][3];
    float scb = pb[r][4] + pb[r + 4][4];
    float* orow = out + (size_t)(row0 + r) * OUT_COLS;
    orow[0] = RGASF * scp;
    orow[1] = RGASF * rs_T[r] * sh;
    orow[2] = RGASF * ss;
    orow[3 + NR + 1] = 0.5f * (sca + 1.0f / scb);
  }

  // ======== Concurrent worker stages (no barriers between them) ===========
  if (tid < 200) {
    // ---- Stage B: this block's 400-q half; thread owns a q-pair ----
    const int q0 = h * 400 + tid * 2;
    float acc[2][RPB];
#pragma unroll
    for (int qi = 0; qi < 2; ++qi)
#pragma unroll
      for (int b = 0; b < RPB; ++b) acc[qi][b] = 0.0f;
#pragma unroll 4
    for (int s2 = 0; s2 < S; ++s2) {
      float2 e = *(const float2*)&eff[(size_t)s2 * NR + q0];
      float4 xq = XL[s2];
#pragma unroll
      for (int b = 0; b < RPB; ++b) {
        acc[0][b] = fmaf(elem(xq, b), e.x, acc[0][b]);
        acc[1][b] = fmaf(elem(xq, b), e.y, acc[1][b]);
      }
    }
    float2 t3 = *(const float2*)&i3b[q0];
#pragma unroll
    for (int qi = 0; qi < 2; ++qi) {
      float tq = qi ? t3.y : t3.x;
      float base = 1.0f - tq;
#pragma unroll
      for (int b = 0; b < RPB; ++b)
        out[(size_t)(row0 + b) * OUT_COLS + 3 + q0 + qi] =
            fmaf(acc[qi][b] * rs_cfac[b], tq, base);
    }
  } else if (tid >= 256 && tid < 384 && h == 0) {
    // ---- Stage C: viscosity (full i-sum, h==0 only); thread owns row i ----
    const int i = tid - 256;
    float contrib[RPB] = {0.0f, 0.0f, 0.0f, 0.0f};
    if (i < S) {
      float d0[RPB], d1[RPB], d2[RPB];
#pragma unroll
      for (int b = 0; b < RPB; ++b) { d0[b] = 0; d1[b] = 0; d2[b] = 0; }
      if (PRE) {
        const float* pm0 = pm + i * 100;
        const float* pm1 = pm + 10000 + i * 100;
        const float* pm2 = pm + 20000 + i * 100;
#pragma unroll 2
        for (int k4 = 0; k4 < S; k4 += 4) {
          float4 a0q = *(const float4*)&pm0[k4];
          float4 a1q = *(const float4*)&pm1[k4];
          float4 a2q = *(const float4*)&pm2[k4];
#pragma unroll
          for (int kk = 0; kk < 4; ++kk) {
            float4 xq = XL[k4 + kk];
            float4 u1q = U1[k4 + kk];
            float4 u2q = U2[k4 + kk];
            float m0 = elem(a0q, kk), m1 = elem(a1q, kk), m2 = elem(a2q, kk);
#pragma unroll
            for (int b = 0; b < RPB; ++b) {
              d0[b] = fmaf(m0, elem(xq, b), d0[b]);
              d1[b] = fmaf(m1, elem(u1q, b), d1[b]);
              d2[b] = fmaf(m2, elem(u2q, b), d2[b]);
            }
          }
        }
      } else {
        const float mwi = mwl[i];
        const float lmi = ilm[i].y;
#pragma unroll 4
        for (int k = 0; k < S; ++k) {
          float2 il = ilm[k];
          float A = 0.35355339059327373f *
                    __builtin_amdgcn_rsqf(1.0f + mwi * il.x);
          float B4 = __builtin_amdgcn_exp2f(0.25f * (il.y - lmi));
          float m1 = A * B4, m2 = m1 * B4;
          float4 xq = XL[k];
          float4 u1q = U1[k];
          float4 u2q = U2[k];
#pragma unroll
          for (int b = 0; b < RPB; ++b) {
            d0[b] = fmaf(A, elem(xq, b), d0[b]);
            d1[b] = fmaf(m1, elem(u1q, b), d1[b]);
            d2[b] = fmaf(m2, elem(u2q, b), d2[b]);
          }
        }
      }
      float4 vq = VL[i];
      float4 xiq = XL[i];
#pragma unroll
      for (int b = 0; b < RPB; ++b) {
        float vi = elem(vq, b);
        float den = d0[b] + 2.0f * sqrtf(vi) * d1[b] + vi * d2[b];
        contrib[b] = elem(xiq, b) * vi * __builtin_amdgcn_rcpf(den);
      }
    }
#pragma unroll
    for (int b = 0; b < RPB; ++b) contrib[b] = wave_sum(contrib[b]);
    if (lane == 0) {
#pragma unroll
      for (int b = 0; b < RPB; ++b) psum[wid - 4][b] = contrib[b];
    }
  } else if (tid >= 384 && tid < 484) {
    // ---- Stage D: this block's 50-k half; thread owns (k, j-half) ----
    const int td = tid - 384;
    const int kk = td % 50;
    const int jh = td / 50;
    const int k = h * 50 + kk;
    const int j0 = jh * 50;
    float Lb[RPB], acc4[RPB];
#pragma unroll
    for (int b = 0; b < RPB; ++b) { Lb[b] = rs_L[b]; acc4[b] = 0.0f; }
    const float* bp = bdiff_poly + k;
#pragma unroll 2
    for (int j = j0; j < j0 + 50; ++j) {
      float c0 = bp[j * 100];
      float c1 = bp[10000 + j * 100];
      float c2 = bp[20000 + j * 100];
      float c3 = bp[30000 + j * 100];
      float c4 = bp[40000 + j * 100];
      float4 xq = XL[j];
      const bool diag = (j == k);
#pragma unroll
      for (int b = 0; b < RPB; ++b) {
        float p = fmaf(c0, Lb[b], c1);
        p = fmaf(p, Lb[b], c2);
        p = fmaf(p, Lb[b], c3);
        p = fmaf(p, Lb[b], c4);
        float r = diag ? 0.0f : __builtin_amdgcn_rcpf(p);
        acc4[b] = fmaf(elem(xq, b), r, acc4[b]);
      }
    }
    if (jh == 0) {
#pragma unroll
      for (int b = 0; b < RPB; ++b) xjd[kk][b] = acc4[b];
    } else {
      // stash second half in registers; combined after the barrier
#pragma unroll
      for (int b = 0; b < RPB; ++b) Lb[b] = acc4[b];  // reuse Lb as stash
    }
    __syncthreads();
    if (jh == 1) {
      float4 xkq = XL[k];
      float mwk = mwl[k];
#pragma unroll
      for (int b = 0; b < RPB; ++b) {
        float tot = xjd[kk][b] + Lb[b];
        float num = rs_mW[b] - elem(xkq, b) * mwk;   // XjWj
        out[(size_t)(row0 + b) * OUT_COLS + 3 + NR + 2 + k] =
            num * __builtin_amdgcn_rcpf(tot) * rs_scale[b];
      }
    }
    return;  // D threads done (they passed the barrier)
  }
  __syncthreads();

  if (h == 0 && tid < RPB) {
    out[(size_t)(row0 + tid) * OUT_COLS + 3 + NR] =
        psum[0][tid] + psum[1][tid];   // viscosities
  }
}

} // namespace

extern "C" void kernel_launch(void* const* d_in, const int* in_sizes, int n_in,
                              void* d_out, int out_size, void* d_ws, size_t ws_size,
                              hipStream_t stream) {
  const float* TPY        = (const float*)d_in[0];
  const float* mwp        = (const float*)d_in[1];
  const float* nasa_low   = (const float*)d_in[2];
  const float* nasa_high  = (const float*)d_in[3];
  const float* eff        = (const float*)d_in[4];
  const float* i3b        = (const float*)d_in[5];
  const float* visc_poly  = (const float*)d_in[6];
  const float* cond_poly  = (const float*)d_in[7];
  const float* bdiff_poly = (const float*)d_in[8];
  float* out = (float*)d_out;
  float* pm  = (float*)d_ws;

  const int B = 2048;
  dim3 grid((B / RPB) * 2);
  if (ws_size >= PHI_WS_BYTES) {
    phi_precompute<<<40, 256, 0, stream>>>(mwp, pm);
    chem_props_kernel<true><<<grid, NTH, 0, stream>>>(
        TPY, mwp, nasa_low, nasa_high, eff, i3b,
        visc_poly, cond_poly, bdiff_poly, pm, out);
  } else {
    chem_props_kernel<false><<<grid, NTH, 0, stream>>>(
        TPY, mwp, nasa_low, nasa_high, eff, i3b,
        visc_poly, cond_poly, bdiff_poly, nullptr, out);
  }
}

// Round 8
// 105.197 us; speedup vs baseline: 1.4181x; 1.1520x over previous
//
#include <hip/hip_runtime.h>
#include <math.h>

namespace {

constexpr int S = 100;
constexpr int NR = 800;
constexpr int RPB = 4;           // batch rows per block
constexpr int NTH = 1024;        // 16 waves
constexpr int IN_COLS = 2 + S;   // 102
constexpr int OUT_COLS = 3 + NR + 2 + S; // 905
constexpr float RGASF = 8314.46261815324f;
constexpr float ATMF = 101325.0f;
constexpr size_t PHI_WS_BYTES = 3 * 10000 * sizeof(float);

__device__ __forceinline__ float wave_sum(float v) {
#pragma unroll
  for (int off = 32; off; off >>= 1) v += __shfl_xor(v, off);
  return v;
}

__device__ __forceinline__ float elem(const float4& v, int i) {
  return ((const float*)&v)[i];
}

// Batch-independent Wilke pair constants: m0 = A, m1 = A*B4, m2 = A*B4^2
__global__ __launch_bounds__(256)
void phi_precompute(const float* __restrict__ mw, float* __restrict__ pm) {
  int idx = blockIdx.x * 256 + threadIdx.x;
  if (idx >= 10000) return;
  int i = idx / 100, k = idx % 100;
  float mwi = mw[i], mwk = mw[k];
  float A = 0.35355339059327373f *
            __builtin_amdgcn_rsqf(1.0f + mwi * __builtin_amdgcn_rcpf(mwk));
  float B4 = __builtin_amdgcn_exp2f(0.25f * (__log2f(mwk) - __log2f(mwi)));
  pm[idx] = A;
  pm[10000 + idx] = A * B4;
  pm[20000 + idx] = A * B4 * B4;
}

template <bool PRE>
__global__ __launch_bounds__(NTH, 8)
void chem_props_kernel(const float* __restrict__ TPY,
                       const float* __restrict__ mw,
                       const float* __restrict__ nasa_low,
                       const float* __restrict__ nasa_high,
                       const float* __restrict__ eff,
                       const float* __restrict__ i3b,
                       const float* __restrict__ visc_poly,
                       const float* __restrict__ cond_poly,
                       const float* __restrict__ bdiff_poly,
                       const float* __restrict__ pm,
                       float* __restrict__ out)
{
  __shared__ __align__(16) float4 XL[S];   // X[s][b] quad
  __shared__ __align__(16) float4 U1[S];   // X/sqrt(visc)
  __shared__ __align__(16) float4 U2[S];   // X/visc
  __shared__ __align__(16) float4 VL[S];   // visc
  __shared__ float mwl[S];
  __shared__ float2 ilm[S];                // {1/mw, log2(mw)}
  __shared__ float pa[8][2];               // half-row partials (y, y/mw)
  __shared__ float pb[8][5];               // thermo partials
  __shared__ float rs_L[RPB], rs_cfac[RPB], rs_mW[RPB], rs_scale[RPB], rs_T[RPB];
  __shared__ float psum[2][RPB];           // viscosity-sum wave partials
  __shared__ __align__(16) float xjd[S][RPB]; // D combine (atomic)

  const int tid = threadIdx.x;
  const int wid = tid >> 6;
  const int lane = tid & 63;
  const int row0 = blockIdx.x * RPB;

  if (tid < S * RPB) (&xjd[0][0])[tid] = 0.0f;
  if (tid < S) {
    float m = mw[tid];
    mwl[tid] = m;
    ilm[tid] = make_float2(1.0f / m, __log2f(m));
  }
  __syncthreads();

  // ============ Stage A: per-row species state (waves 0-7, 2/row) ==========
  float T = 0.f, P = 0.f, L = 0.f, y = 0.f, im = 0.f;
  int row = 0, half = 0, s = 0;
  bool valid = false;
  if (wid < 8) {
    row = wid & 3;
    half = wid >> 2;
    const float* rowp = TPY + (size_t)(row0 + row) * IN_COLS;
    T = fmaxf(rowp[0], 200.0f);
    P = rowp[1];
    L = __logf(T);
    s = half * 64 + lane;
    valid = (s < S);
    y = valid ? fmaxf(rowp[2 + s], 0.0f) : 0.0f;
    im = valid ? ilm[s].x : 0.0f;
    float py = wave_sum(y);
    float pw = wave_sum(y * im);
    if (lane == 0) { pa[wid][0] = py; pa[wid][1] = pw; }
  }
  __syncthreads();
  if (wid < 8) {
    float T2 = T * T, T3 = T2 * T, T4 = T2 * T2;
    float invT = 1.0f / T;
    float ysum = pa[row][0] + pa[row + 4][0];
    float wsum = pa[row][1] + pa[row + 4][1];
    float invy = 1.0f / ysum;
    float mW = ysum / wsum;
    float cfac = P / (RGASF * T);
    float lnP = __logf(P * (1.0f / ATMF));
    const float* nasa = (T <= 1000.0f) ? nasa_low : nasa_high;

    float cpx = 0.0f, hy = 0.0f, sy = 0.0f, condA = 0.0f, condB = 0.0f;
    if (valid) {
      float yn = y * invy;
      float x = fmaxf(yn * mW * im, 1e-12f);
      const float* a = nasa + s * 7;
      float a0 = a[0], a1 = a[1], a2 = a[2], a3 = a[3],
            a4 = a[4], a5 = a[5], a6 = a[6];
      float cp = a0 + a1 * T + a2 * T2 + a3 * T3 + a4 * T4;
      float Ht = a0 + 0.5f * a1 * T + (1.0f / 3.0f) * a2 * T2
               + 0.25f * a3 * T3 + 0.2f * a4 * T4 + a5 * invT;
      float S0r = a0 * L + a1 * T + 0.5f * a2 * T2
                + (1.0f / 3.0f) * a3 * T3 + 0.25f * a4 * T4 + a6;
      cpx = cp * x;
      hy = Ht * im * yn;
      sy = (S0r - __logf(x) - lnP) * im * yn;

      float v = visc_poly[0 * S + s];
      v = fmaf(v, L, visc_poly[1 * S + s]);
      v = fmaf(v, L, visc_poly[2 * S + s]);
      v = fmaf(v, L, visc_poly[3 * S + s]);
      v = fmaf(v, L, visc_poly[4 * S + s]);
      float c = cond_poly[0 * S + s];
      c = fmaf(c, L, cond_poly[1 * S + s]);
      c = fmaf(c, L, cond_poly[2 * S + s]);
      c = fmaf(c, L, cond_poly[3 * S + s]);
      c = fmaf(c, L, cond_poly[4 * S + s]);
      condA = x * c;
      condB = x / c;
      ((float*)&XL[s])[row] = x;
      ((float*)&VL[s])[row] = v;
      ((float*)&U1[s])[row] = x * __builtin_amdgcn_rsqf(v);
      ((float*)&U2[s])[row] = x * __builtin_amdgcn_rcpf(v);
    }
    float scp = wave_sum(cpx);
    float sh = wave_sum(hy);
    float ss = wave_sum(sy);
    float sca = wave_sum(condA);
    float scb = wave_sum(condB);
    if (lane == 0) {
      pb[wid][0] = scp; pb[wid][1] = sh; pb[wid][2] = ss;
      pb[wid][3] = sca; pb[wid][4] = scb;
      if (half == 0) {
        rs_L[row] = L;
        rs_T[row] = T;
        rs_cfac[row] = cfac;
        rs_mW[row] = mW;
        rs_scale[row] = ATMF / (mW * P);
      }
    }
  }
  __syncthreads();

  // scalar outputs
  if (tid < RPB) {
    const int r = tid;
    float scp = pb[r][0] + pb[r + 4][0];
    float sh  = pb[r][1] + pb[r + 4][1];
    float ss  = pb[r][2] + pb[r + 4][2];
    float sca = pb[r][3] + pb[r + 4][3];
    float scb = pb[r][4] + pb[r + 4][4];
    float* orow = out + (size_t)(row0 + r) * OUT_COLS;
    orow[0] = RGASF * scp;
    orow[1] = RGASF * rs_T[r] * sh;
    orow[2] = RGASF * ss;
    orow[3 + NR + 1] = 0.5f * (sca + 1.0f / scb);
  }

  // ======== Concurrent worker stages (no barriers between them) ===========
  if (tid < 400) {
    // ---- Stage B: thread owns a q-pair (400 threads) ----
    const int q0 = tid * 2;
    float acc0[RPB], acc1[RPB];
#pragma unroll
    for (int b = 0; b < RPB; ++b) { acc0[b] = 0.0f; acc1[b] = 0.0f; }
#pragma unroll 4
    for (int s2 = 0; s2 < S; ++s2) {
      float2 e = *(const float2*)&eff[(size_t)s2 * NR + q0];
      float4 xq = XL[s2];
#pragma unroll
      for (int b = 0; b < RPB; ++b) {
        acc0[b] = fmaf(elem(xq, b), e.x, acc0[b]);
        acc1[b] = fmaf(elem(xq, b), e.y, acc1[b]);
      }
    }
    float2 t3 = *(const float2*)&i3b[q0];
    float base0 = 1.0f - t3.x, base1 = 1.0f - t3.y;
#pragma unroll
    for (int b = 0; b < RPB; ++b) {
      float* op = out + (size_t)(row0 + b) * OUT_COLS + 3 + q0;
      op[0] = fmaf(acc0[b] * rs_cfac[b], t3.x, base0);
      op[1] = fmaf(acc1[b] * rs_cfac[b], t3.y, base1);
    }
  } else if (tid >= 448 && tid < 576) {
    // ---- Stage C: viscosity; thread owns row i (waves 7-8) ----
    const int i = tid - 448;
    float contrib[RPB] = {0.0f, 0.0f, 0.0f, 0.0f};
    if (i < S) {
      float d0[RPB], d1[RPB], d2[RPB];
#pragma unroll
      for (int b = 0; b < RPB; ++b) { d0[b] = 0; d1[b] = 0; d2[b] = 0; }
      if (PRE) {
        const float* pm0 = pm + i * 100;
        const float* pm1 = pm + 10000 + i * 100;
        const float* pm2 = pm + 20000 + i * 100;
#pragma unroll 2
        for (int k4 = 0; k4 < S; k4 += 4) {
          float4 a0q = *(const float4*)&pm0[k4];
          float4 a1q = *(const float4*)&pm1[k4];
          float4 a2q = *(const float4*)&pm2[k4];
#pragma unroll
          for (int kk = 0; kk < 4; ++kk) {
            float4 xq = XL[k4 + kk];
            float4 u1q = U1[k4 + kk];
            float4 u2q = U2[k4 + kk];
            float m0 = elem(a0q, kk), m1 = elem(a1q, kk), m2 = elem(a2q, kk);
#pragma unroll
            for (int b = 0; b < RPB; ++b) {
              d0[b] = fmaf(m0, elem(xq, b), d0[b]);
              d1[b] = fmaf(m1, elem(u1q, b), d1[b]);
              d2[b] = fmaf(m2, elem(u2q, b), d2[b]);
            }
          }
        }
      } else {
        const float mwi = mwl[i];
        const float lmi = ilm[i].y;
#pragma unroll 4
        for (int k = 0; k < S; ++k) {
          float2 il = ilm[k];
          float A = 0.35355339059327373f *
                    __builtin_amdgcn_rsqf(1.0f + mwi * il.x);
          float B4 = __builtin_amdgcn_exp2f(0.25f * (il.y - lmi));
          float m1 = A * B4, m2 = m1 * B4;
          float4 xq = XL[k];
          float4 u1q = U1[k];
          float4 u2q = U2[k];
#pragma unroll
          for (int b = 0; b < RPB; ++b) {
            d0[b] = fmaf(A, elem(xq, b), d0[b]);
            d1[b] = fmaf(m1, elem(u1q, b), d1[b]);
            d2[b] = fmaf(m2, elem(u2q, b), d2[b]);
          }
        }
      }
      float4 vq = VL[i];
      float4 xiq = XL[i];
#pragma unroll
      for (int b = 0; b < RPB; ++b) {
        float vi = elem(vq, b);
        float den = d0[b] + 2.0f * sqrtf(vi) * d1[b] + vi * d2[b];
        contrib[b] = elem(xiq, b) * vi * __builtin_amdgcn_rcpf(den);
      }
    }
#pragma unroll
    for (int b = 0; b < RPB; ++b) contrib[b] = wave_sum(contrib[b]);
    if (lane == 0) {
#pragma unroll
      for (int b = 0; b < RPB; ++b) psum[wid - 7][b] = contrib[b];
    }
  } else if (tid >= 576 && tid < 976) {
    // ---- Stage D: thread owns (k, j-group of 25); 400 threads ----
    const int t = tid - 576;
    const int k = t % 100;
    const int jg = t / 100;
    const int j0 = jg * 25;
    float Lb[RPB], acc4[RPB];
#pragma unroll
    for (int b = 0; b < RPB; ++b) { Lb[b] = rs_L[b]; acc4[b] = 0.0f; }
    const float* bp = bdiff_poly + k;
#pragma unroll 5
    for (int j = j0; j < j0 + 25; ++j) {
      float c0 = bp[j * 100];
      float c1 = bp[10000 + j * 100];
      float c2 = bp[20000 + j * 100];
      float c3 = bp[30000 + j * 100];
      float c4 = bp[40000 + j * 100];
      float4 xq = XL[j];
      const bool diag = (j == k);
#pragma unroll
      for (int b = 0; b < RPB; ++b) {
        float p = fmaf(c0, Lb[b], c1);
        p = fmaf(p, Lb[b], c2);
        p = fmaf(p, Lb[b], c3);
        p = fmaf(p, Lb[b], c4);
        float r = diag ? 0.0f : __builtin_amdgcn_rcpf(p);
        acc4[b] = fmaf(elem(xq, b), r, acc4[b]);
      }
    }
#pragma unroll
    for (int b = 0; b < RPB; ++b) atomicAdd(&xjd[k][b], acc4[b]);
  }
  __syncthreads();

  // ============ Final writes ==============================================
  if (tid < RPB) {
    out[(size_t)(row0 + tid) * OUT_COLS + 3 + NR] =
        psum[0][tid] + psum[1][tid];   // viscosities
  }
  if (tid < S) {
    const int k = tid;
    float4 xkq = XL[k];
    float mwk = mwl[k];
#pragma unroll
    for (int b = 0; b < RPB; ++b) {
      float num = rs_mW[b] - elem(xkq, b) * mwk;     // XjWj
      out[(size_t)(row0 + b) * OUT_COLS + 3 + NR + 2 + k] =
          num * __builtin_amdgcn_rcpf(xjd[k][b]) * rs_scale[b];
    }
  }
}

} // namespace

extern "C" void kernel_launch(void* const* d_in, const int* in_sizes, int n_in,
                              void* d_out, int out_size, void* d_ws, size_t ws_size,
                              hipStream_t stream) {
  const float* TPY        = (const float*)d_in[0];
  const float* mwp        = (const float*)d_in[1];
  const float* nasa_low   = (const float*)d_in[2];
  const float* nasa_high  = (const float*)d_in[3];
  const float* eff        = (const float*)d_in[4];
  const float* i3b        = (const float*)d_in[5];
  const float* visc_poly  = (const float*)d_in[6];
  const float* cond_poly  = (const float*)d_in[7];
  const float* bdiff_poly = (const float*)d_in[8];
  float* out = (float*)d_out;
  float* pm  = (float*)d_ws;

  const int B = 2048;
  dim3 grid(B / RPB);
  if (ws_size >= PHI_WS_BYTES) {
    phi_precompute<<<40, 256, 0, stream>>>(mwp, pm);
    chem_props_kernel<true><<<grid, NTH, 0, stream>>>(
        TPY, mwp, nasa_low, nasa_high, eff, i3b,
        visc_poly, cond_poly, bdiff_poly, pm, out);
  } else {
    chem_props_kernel<false><<<grid, NTH, 0, stream>>>(
        TPY, mwp, nasa_low, nasa_high, eff, i3b,
        visc_poly, cond_poly, bdiff_poly, nullptr, out);
  }
}

// Round 9
// 100.858 us; speedup vs baseline: 1.4791x; 1.0430x over previous
//
#include <hip/hip_runtime.h>
#include <math.h>

namespace {

constexpr int S = 100;
constexpr int NR = 800;
constexpr int RPT = 8;            // rows per tile (kernel 2)
constexpr int IN_COLS = 2 + S;    // 102
constexpr int OUT_COLS = 3 + NR + 2 + S; // 905
constexpr float RGASF = 8314.46261815324f;
constexpr float ATMF = 101325.0f;

// d_ws layout (floats)
constexpr size_t OFF_X  = 0;          // 2048*100
constexpr size_t OFF_U1 = 204800;     // X/sqrt(visc)
constexpr size_t OFF_U2 = 409600;     // X/visc
constexpr size_t OFF_V  = 614400;     // visc
constexpr size_t OFF_RS = 819200;     // 2048*4 : {L, cfac, mW, scale}

__device__ __forceinline__ float wave_sum(float v) {
#pragma unroll
  for (int off = 32; off; off >>= 1) v += __shfl_xor(v, off);
  return v;
}

__device__ __forceinline__ float elem(const float4& v, int i) {
  return ((const float*)&v)[i];
}

// ================= Kernel 1: per-row species state + scalars ===============
__global__ __launch_bounds__(512)
void stage_a_kernel(const float* __restrict__ TPY,
                    const float* __restrict__ mw,
                    const float* __restrict__ nasa_low,
                    const float* __restrict__ nasa_high,
                    const float* __restrict__ visc_poly,
                    const float* __restrict__ cond_poly,
                    float* __restrict__ ws,
                    float* __restrict__ out)
{
  __shared__ float imw[S];
  const int tid = threadIdx.x;
  const int wid = tid >> 6;
  const int lane = tid & 63;
  if (tid < S) imw[tid] = 1.0f / mw[tid];
  __syncthreads();

  const int row = blockIdx.x * 8 + wid;
  const float* rowp = TPY + (size_t)row * IN_COLS;
  float T = fmaxf(rowp[0], 200.0f);
  float P = rowp[1];
  float L = __logf(T);
  float T2 = T * T, T3 = T2 * T, T4 = T2 * T2;
  float invT = 1.0f / T;

  int sA = lane, sB = lane + 64;
  bool hasB = (sB < S);
  float y0 = fmaxf(rowp[2 + sA], 0.0f);
  float y1 = hasB ? fmaxf(rowp[2 + sB], 0.0f) : 0.0f;
  float im0 = imw[sA];
  float im1 = hasB ? imw[sB] : 0.0f;

  float ysum = wave_sum(y0 + y1);
  float invy = 1.0f / ysum;
  float wsum = wave_sum(y0 * im0 + y1 * im1);
  float mW = ysum / wsum;
  float cfac = P / (RGASF * T);
  float lnP = __logf(P * (1.0f / ATMF));
  const float* nasa = (T <= 1000.0f) ? nasa_low : nasa_high;

  float cpx = 0.0f, hy = 0.0f, sy = 0.0f, condA = 0.0f, condB = 0.0f;
#pragma unroll
  for (int t = 0; t < 2; ++t) {
    int s = t ? sB : sA;
    if (s < S) {
      float y = t ? y1 : y0;
      float im = t ? im1 : im0;
      float yn = y * invy;
      float x = fmaxf(yn * mW * im, 1e-12f);
      const float* a = nasa + s * 7;
      float a0 = a[0], a1 = a[1], a2 = a[2], a3 = a[3],
            a4 = a[4], a5 = a[5], a6 = a[6];
      float cp = a0 + a1 * T + a2 * T2 + a3 * T3 + a4 * T4;
      float Ht = a0 + 0.5f * a1 * T + (1.0f / 3.0f) * a2 * T2
               + 0.25f * a3 * T3 + 0.2f * a4 * T4 + a5 * invT;
      float S0r = a0 * L + a1 * T + 0.5f * a2 * T2
                + (1.0f / 3.0f) * a3 * T3 + 0.25f * a4 * T4 + a6;
      cpx += cp * x;
      hy += Ht * im * yn;
      sy += (S0r - __logf(x) - lnP) * im * yn;

      float v = visc_poly[0 * S + s];
      v = fmaf(v, L, visc_poly[1 * S + s]);
      v = fmaf(v, L, visc_poly[2 * S + s]);
      v = fmaf(v, L, visc_poly[3 * S + s]);
      v = fmaf(v, L, visc_poly[4 * S + s]);
      float c = cond_poly[0 * S + s];
      c = fmaf(c, L, cond_poly[1 * S + s]);
      c = fmaf(c, L, cond_poly[2 * S + s]);
      c = fmaf(c, L, cond_poly[3 * S + s]);
      c = fmaf(c, L, cond_poly[4 * S + s]);
      condA += x * c;
      condB += x / c;

      size_t o = (size_t)row * 100 + s;
      ws[OFF_X + o]  = x;
      ws[OFF_V + o]  = v;
      ws[OFF_U1 + o] = x * __builtin_amdgcn_rsqf(v);
      ws[OFF_U2 + o] = x * __builtin_amdgcn_rcpf(v);
    }
  }
  float scp = wave_sum(cpx);
  float sh = wave_sum(hy);
  float ss = wave_sum(sy);
  float sca = wave_sum(condA);
  float scb = wave_sum(condB);
  if (lane == 0) {
    float* orow = out + (size_t)row * OUT_COLS;
    orow[0] = RGASF * scp;
    orow[1] = RGASF * T * sh;
    orow[2] = RGASF * ss;
    orow[3 + NR + 1] = 0.5f * (sca + 1.0f / scb);
    float* rs = ws + OFF_RS + (size_t)row * 4;
    rs[0] = L;
    rs[1] = cfac;
    rs[2] = mW;
    rs[3] = ATMF / (mW * P);
  }
}

// ================= Kernel 2: workers (B slices, C, D slices) ===============
// grid = (2048/RPT) * 7 ; job 0-3 = B-slices(200q), 4 = C, 5-6 = D-slices(50k)
__global__ __launch_bounds__(256, 6)
void worker_kernel(const float* __restrict__ eff,
                   const float* __restrict__ i3b,
                   const float* __restrict__ bdiff,
                   const float* __restrict__ mw,
                   const float* __restrict__ ws,
                   float* __restrict__ out)
{
  __shared__ __align__(16) float X8[S][RPT];
  __shared__ __align__(16) float U18[S][RPT];
  __shared__ __align__(16) float U28[S][RPT];
  __shared__ __align__(16) float V8[S][RPT];
  __shared__ float rs8[RPT][4];
  __shared__ float mwl[S], ilmx[S], ilmy[S];
  __shared__ __align__(16) float den[S][RPT];
  __shared__ __align__(16) float xjd[50][RPT];
  __shared__ float psum[2][RPT];

  const int t = threadIdx.x;
  const int bid = blockIdx.x;
  const int rt = bid / 7;
  const int job = bid - rt * 7;
  const int row0 = rt * RPT;

  // ---- stage LDS from ws (coalesced: ws[row0*100 + idx]) ----
  const float* wsX = ws + OFF_X + (size_t)row0 * 100;
  for (int idx = t; idx < 800; idx += 256)
    X8[idx % 100][idx / 100] = wsX[idx];
  if (job == 4) {
    const float* w1 = ws + OFF_U1 + (size_t)row0 * 100;
    const float* w2 = ws + OFF_U2 + (size_t)row0 * 100;
    const float* wv = ws + OFF_V + (size_t)row0 * 100;
    for (int idx = t; idx < 800; idx += 256) {
      U18[idx % 100][idx / 100] = w1[idx];
      U28[idx % 100][idx / 100] = w2[idx];
      V8[idx % 100][idx / 100] = wv[idx];
      (&den[0][0])[idx] = 0.0f;
    }
  }
  if (job >= 5 && t < 50 * RPT) (&xjd[0][0])[t] = 0.0f;
  if (t < S) {
    float m = mw[t];
    mwl[t] = m;
    ilmx[t] = 1.0f / m;
    ilmy[t] = __log2f(m);
  }
  if (t < RPT * 4) (&rs8[0][0])[t] = ws[OFF_RS + (size_t)row0 * 4 + t];
  __syncthreads();

  if (job < 4) {
    // ---- Stage B slice: q in [job*200, job*200+200) ----
    if (t < 200) {
      const int q = job * 200 + t;
      float acc[RPT];
#pragma unroll
      for (int r = 0; r < RPT; ++r) acc[r] = 0.0f;
#pragma unroll 4
      for (int s = 0; s < S; ++s) {
        float e = eff[(size_t)s * NR + q];
        float4 xa = *(const float4*)&X8[s][0];
        float4 xb = *(const float4*)&X8[s][4];
#pragma unroll
        for (int r = 0; r < 4; ++r) {
          acc[r] = fmaf(elem(xa, r), e, acc[r]);
          acc[4 + r] = fmaf(elem(xb, r), e, acc[4 + r]);
        }
      }
      float t3 = i3b[q];
      float base = 1.0f - t3;
#pragma unroll
      for (int r = 0; r < RPT; ++r)
        out[(size_t)(row0 + r) * OUT_COLS + 3 + q] =
            fmaf(acc[r] * rs8[r][1], t3, base);
    }
  } else if (job == 4) {
    // ---- Stage C: viscosity mixing (full i range, k split in halves) ----
    if (t < 200) {
      const int i = t % 100;
      const int kg = t / 100;
      const float mwi = mwl[i];
      const float lmi = ilmy[i];
      float d0[RPT], d1[RPT], d2[RPT];
#pragma unroll
      for (int r = 0; r < RPT; ++r) { d0[r] = 0; d1[r] = 0; d2[r] = 0; }
      const int k0 = kg * 50;
#pragma unroll 2
      for (int k = k0; k < k0 + 50; ++k) {
        float A = 0.35355339059327373f *
                  __builtin_amdgcn_rsqf(1.0f + mwi * ilmx[k]);
        float B4 = __builtin_amdgcn_exp2f(0.25f * (ilmy[k] - lmi));
        float m1 = A * B4, m2 = m1 * B4;
        float4 xa = *(const float4*)&X8[k][0];
        float4 xb = *(const float4*)&X8[k][4];
        float4 u1a = *(const float4*)&U18[k][0];
        float4 u1b = *(const float4*)&U18[k][4];
        float4 u2a = *(const float4*)&U28[k][0];
        float4 u2b = *(const float4*)&U28[k][4];
#pragma unroll
        for (int r = 0; r < 4; ++r) {
          d0[r] = fmaf(A, elem(xa, r), d0[r]);
          d0[4 + r] = fmaf(A, elem(xb, r), d0[4 + r]);
          d1[r] = fmaf(m1, elem(u1a, r), d1[r]);
          d1[4 + r] = fmaf(m1, elem(u1b, r), d1[4 + r]);
          d2[r] = fmaf(m2, elem(u2a, r), d2[r]);
          d2[4 + r] = fmaf(m2, elem(u2b, r), d2[4 + r]);
        }
      }
#pragma unroll
      for (int r = 0; r < RPT; ++r) {
        float vi = V8[i][r];
        float pden = d0[r] + 2.0f * sqrtf(vi) * d1[r] + vi * d2[r];
        atomicAdd(&den[i][r], pden);
      }
    }
    __syncthreads();
    if (t < 128) {
      float c8[RPT];
#pragma unroll
      for (int r = 0; r < RPT; ++r) c8[r] = 0.0f;
      if (t < 100) {
#pragma unroll
        for (int r = 0; r < RPT; ++r)
          c8[r] = X8[t][r] * V8[t][r] * __builtin_amdgcn_rcpf(den[t][r]);
      }
#pragma unroll
      for (int r = 0; r < RPT; ++r) c8[r] = wave_sum(c8[r]);
      if ((t & 63) == 0) {
#pragma unroll
        for (int r = 0; r < RPT; ++r) psum[t >> 6][r] = c8[r];
      }
    }
    __syncthreads();
    if (t < RPT)
      out[(size_t)(row0 + t) * OUT_COLS + 3 + NR] = psum[0][t] + psum[1][t];
  } else {
    // ---- Stage D slice: k in [koff, koff+50), j split into 5 groups ----
    const int koff = (job - 5) * 50;
    if (t < 250) {
      const int kk = t % 50;
      const int jg = t / 50;
      const int k = koff + kk;
      const int j0 = jg * 20;
      float Lb[RPT], acc8[RPT];
#pragma unroll
      for (int r = 0; r < RPT; ++r) { Lb[r] = rs8[r][0]; acc8[r] = 0.0f; }
      const float* bp = bdiff + k;
#pragma unroll 2
      for (int j = j0; j < j0 + 20; ++j) {
        float c0 = bp[j * 100];
        float c1 = bp[10000 + j * 100];
        float c2 = bp[20000 + j * 100];
        float c3 = bp[30000 + j * 100];
        float c4 = bp[40000 + j * 100];
        float4 xa = *(const float4*)&X8[j][0];
        float4 xb = *(const float4*)&X8[j][4];
        const bool diag = (j == k);
#pragma unroll
        for (int r = 0; r < RPT; ++r) {
          float p = fmaf(c0, Lb[r], c1);
          p = fmaf(p, Lb[r], c2);
          p = fmaf(p, Lb[r], c3);
          p = fmaf(p, Lb[r], c4);
          float rr = diag ? 0.0f : __builtin_amdgcn_rcpf(p);
          float xv = (r < 4) ? elem(xa, r) : elem(xb, r - 4);
          acc8[r] = fmaf(xv, rr, acc8[r]);
        }
      }
#pragma unroll
      for (int r = 0; r < RPT; ++r) atomicAdd(&xjd[kk][r], acc8[r]);
    }
    __syncthreads();
    if (t < 50 * RPT) {
      const int kk = t % 50;
      const int r = t / 50;
      const int k = koff + kk;
      float tot = xjd[kk][r];
      float num = rs8[r][2] - X8[k][r] * mwl[k];   // XjWj
      out[(size_t)(row0 + r) * OUT_COLS + 3 + NR + 2 + k] =
          num * __builtin_amdgcn_rcpf(tot) * rs8[r][3];
    }
  }
}

} // namespace

extern "C" void kernel_launch(void* const* d_in, const int* in_sizes, int n_in,
                              void* d_out, int out_size, void* d_ws, size_t ws_size,
                              hipStream_t stream) {
  const float* TPY        = (const float*)d_in[0];
  const float* mwp        = (const float*)d_in[1];
  const float* nasa_low   = (const float*)d_in[2];
  const float* nasa_high  = (const float*)d_in[3];
  const float* eff        = (const float*)d_in[4];
  const float* i3b        = (const float*)d_in[5];
  const float* visc_poly  = (const float*)d_in[6];
  const float* cond_poly  = (const float*)d_in[7];
  const float* bdiff_poly = (const float*)d_in[8];
  float* out = (float*)d_out;
  float* ws  = (float*)d_ws;

  const int B = 2048;
  stage_a_kernel<<<B / 8, 512, 0, stream>>>(
      TPY, mwp, nasa_low, nasa_high, visc_poly, cond_poly, ws, out);
  worker_kernel<<<(B / RPT) * 7, 256, 0, stream>>>(
      eff, i3b, bdiff_poly, mwp, ws, out);
}